// Round 15
// baseline (368.464 us; speedup 1.0000x reference)
//
#include <hip/hip_runtime.h>
#include <hip/hip_bf16.h>
#include <math.h>
#include <stdint.h>

#define CC   256
#define HW   (128*128)       // 16384
#define MAT  (CC*CC)         // 65536
#define NBH  2048
#define N0   4096
#define N1   8192
#define N2   16384

typedef __attribute__((ext_vector_type(8))) short bf16x8;
typedef __attribute__((ext_vector_type(4))) float f32x4;
typedef __attribute__((address_space(3))) uint32_t lds_u32_t;
typedef __attribute__((address_space(1))) const uint32_t glb_u32_t;

// ---------------------------------------------------------------------------
// k_mats1 / k_mats2: tiny weight-product kernels (unchanged).
// ---------------------------------------------------------------------------
__global__ __launch_bounds__(256) void k_mats1(
    const float* __restrict__ Wp, const float* __restrict__ Wf,
    const float* __restrict__ Wo, const float* __restrict__ Wfu,
    __hip_bfloat16* __restrict__ A, float* __restrict__ E)
{
    int idx = blockIdx.x;
    int t = threadIdx.x;
    if (idx < 3*CC) {
        int i = idx >> 8, c = idx & 255;
        const float* wf = Wf + (size_t)i*MAT;
        const float* wp = Wp + (size_t)i*MAT;
        float acc = 0.f;
        for (int o = 0; o < CC; ++o)
            acc += wf[o*CC + c] * wp[o*CC + t];
        A[(size_t)i*512*CC + (size_t)c*CC + t] = __float2bfloat16(acc);
    } else {
        idx -= 3*CC;
        int i = idx >> 8, o = idx & 255;
        const float* wo = Wo + (size_t)i*MAT;
        const float* wfu = Wfu + (size_t)o*(3*CC) + i*CC;
        float acc = 0.f;
        for (int c3 = 0; c3 < CC; ++c3)
            acc += wfu[c3] * wo[c3*CC + t];
        E[(size_t)i*MAT + (size_t)o*CC + t] = acc;
    }
}

__global__ __launch_bounds__(256) void k_mats2(
    const float* __restrict__ Wp, const float* __restrict__ E,
    __hip_bfloat16* __restrict__ A)
{
    int idx = blockIdx.x;
    int i = idx >> 8, o = idx & 255;
    int t = threadIdx.x;
    const float* e = E + (size_t)i*MAT + (size_t)o*CC;
    const float* wp = Wp + (size_t)i*MAT;
    float acc = 0.f;
    for (int c = 0; c < CC; ++c)
        acc += e[c] * wp[c*CC + t];
    A[(size_t)i*512*CC + (size_t)(256+o)*CC + t] = __float2bfloat16(acc);
}

// ---------------------------------------------------------------------------
// k_trans: fused transpose + bf16 cast + pooling bins.
// Block = (b, ct, ht): tile c0..c0+15 x h0..h0+15. Reads x in 4KB contiguous
// chunks (16 staged float4/thread), LDS tile [i][j][w] bf16, writes
// xT[b][h][c][w] bf16 in 4KB contiguous chunks, and binsG[b][c][h][8] fp32.
// ---------------------------------------------------------------------------
__global__ __launch_bounds__(256, 4) void k_trans(
    const float* __restrict__ x, __hip_bfloat16* __restrict__ xT,
    float* __restrict__ binsG)
{
    int blk = blockIdx.x;                // b*128 + ct*8 + ht
    int b  = blk >> 7;
    int ct = (blk >> 3) & 15;
    int ht = blk & 7;
    int c0 = ct*16, h0 = ht*16;
    int t = threadIdx.x;

    __shared__ ushort xt[16*16*128];     // [i][j][w], 65536 B
    __shared__ float  bl[16*128];        // [i][j*8+bin], 8192 B

    #pragma unroll 1
    for (int batch = 0; batch < 2; ++batch) {
        float4 v[16];
        #pragma unroll
        for (int k = 0; k < 16; ++k) {
            int kk = batch*16 + k;
            int i = kk >> 1, j8 = (kk & 1)*8;
            const float4* src = (const float4*)x +
                ((size_t)(b*256 + c0 + i)*128 + h0 + j8)*32 + t;
            v[k] = *src;                 // 4KB contiguous per (i, j8) chunk
        }
        #pragma unroll
        for (int k = 0; k < 16; ++k) {
            int kk = batch*16 + k;
            int i = kk >> 1;
            int j = (kk & 1)*8 + (t >> 5);
            int w4 = t & 31;
            float s = v[k].x + v[k].y + v[k].z + v[k].w;
            s += __shfl_xor(s, 1);
            s += __shfl_xor(s, 2);       // 16-pixel bin sum (fp32)
            if ((w4 & 3) == 0) bl[i*128 + j*8 + (w4 >> 2)] = s;
            union { __hip_bfloat16 h[4]; ushort4 q; } cu;
            cu.h[0] = __float2bfloat16(v[k].x);
            cu.h[1] = __float2bfloat16(v[k].y);
            cu.h[2] = __float2bfloat16(v[k].z);
            cu.h[3] = __float2bfloat16(v[k].w);
            *(ushort4*)&xt[((i*16 + j)*128 + w4*4)] = cu.q;
        }
    }
    __syncthreads();

    // write xT: per j, 16c x 128w = 4KB contiguous
    #pragma unroll 4
    for (int j = 0; j < 16; ++j) {
        size_t base4 = (((size_t)(b*128 + h0 + j)*256 + c0)*128) >> 2; // ushort4
        #pragma unroll
        for (int p = 0; p < 2; ++p) {
            int q = p*256 + t;
            int i = q >> 5, w4 = q & 31;
            ushort4 val = *(const ushort4*)&xt[(i*16 + j)*128 + w4*4];
            ((ushort4*)xT)[base4 + q] = val;
        }
    }
    // write binsG: per c, 16h x 8 bins = 512B contiguous
    #pragma unroll
    for (int it = 0; it < 8; ++it) {
        int q = it*256 + t;              // 0..2047
        int c = q >> 7, rem = q & 127;
        binsG[((size_t)(b*256 + c0 + c)*128 + h0)*8 + rem] = bl[c*128 + rem];
    }
}

// ---------------------------------------------------------------------------
// k_poolB: binsG -> Bt (bf16), unchanged.
// ---------------------------------------------------------------------------
__global__ __launch_bounds__(256) void k_poolB(
    const float* __restrict__ binsG, __hip_bfloat16* __restrict__ Bt)
{
    int bh = blockIdx.x;
    int b = bh >> 7, h = bh & 127;
    int c = threadIdx.x;
    const float* g = binsG + (((size_t)b*256 + c)*128 + h)*8;
    float4 lo = *(const float4*)(g);
    float4 hi = *(const float4*)(g + 4);
    float b8[8] = {lo.x, lo.y, lo.z, lo.w, hi.x, hi.y, hi.z, hi.w};

    __hip_bfloat16* B0 = Bt;
    __hip_bfloat16* B1 = Bt + (size_t)N0*CC;
    __hip_bfloat16* B2 = Bt + (size_t)(N0+N1)*CC;
    B0[((size_t)bh*2 + 0)*CC + c] = __float2bfloat16((b8[0]+b8[1]+b8[2]+b8[3]) * (1.f/64.f));
    B0[((size_t)bh*2 + 1)*CC + c] = __float2bfloat16((b8[4]+b8[5]+b8[6]+b8[7]) * (1.f/64.f));
    #pragma unroll
    for (int j = 0; j < 4; ++j)
        B1[((size_t)bh*4 + j)*CC + c] = __float2bfloat16((b8[2*j]+b8[2*j+1]) * (1.f/32.f));
    #pragma unroll
    for (int j = 0; j < 8; ++j)
        B2[((size_t)bh*8 + j)*CC + c] = __float2bfloat16(b8[j] * (1.f/16.f));
}

// ---------------------------------------------------------------------------
// k_gemm: unchanged (bf16 Cc[bh][512][16] output).
// ---------------------------------------------------------------------------
__global__ __launch_bounds__(128) void k_gemm(
    const __hip_bfloat16* __restrict__ A,
    const __hip_bfloat16* __restrict__ Bt,
    __hip_bfloat16* __restrict__ Cc)
{
    int blk = blockIdx.x;
    int br, lb, LP, poff;
    if (blk < 256)      { br = 0; lb = blk;       LP = 1; poff = 0; }
    else if (blk < 768) { br = 1; lb = blk - 256; LP = 2; poff = 2; }
    else                { br = 2; lb = blk - 768; LP = 3; poff = 6; }
    size_t aoff  = (size_t)br*512*CC;
    size_t btoff = (br == 0) ? 0 : (br == 1 ? (size_t)N0*CC : (size_t)(N0+N1)*CC);
    const __hip_bfloat16* Ab = A  + aoff;
    const __hip_bfloat16* Bb = Bt + btoff;

    int rb = lb & 3, cb = lb >> 2;
    int wv = threadIdx.x >> 6, lane = threadIdx.x & 63;
    int row0 = rb*128 + wv*64;
    int col0 = cb*64;
    int lr = lane & 15, lk = (lane >> 4) * 8;

    f32x4 acc[4][4] = {};
    for (int kk = 0; kk < CC; kk += 32) {
        bf16x8 af[4], bfr[4];
        #pragma unroll
        for (int m = 0; m < 4; ++m)
            af[m] = *reinterpret_cast<const bf16x8*>(Ab + (size_t)(row0 + m*16 + lr)*CC + kk + lk);
        #pragma unroll
        for (int n = 0; n < 4; ++n)
            bfr[n] = *reinterpret_cast<const bf16x8*>(Bb + (size_t)(col0 + n*16 + lr)*CC + kk + lk);
        #pragma unroll
        for (int m = 0; m < 4; ++m)
            #pragma unroll
            for (int n = 0; n < 4; ++n)
                acc[m][n] = __builtin_amdgcn_mfma_f32_16x16x32_bf16(af[m], bfr[n], acc[m][n], 0, 0, 0);
    }

    int cr = (lane >> 4) * 4, ccol = lane & 15;
    int pm = (1 << LP) - 1;
    #pragma unroll
    for (int m = 0; m < 4; ++m) {
        #pragma unroll
        for (int n = 0; n < 4; ++n) {
            int colg = col0 + n*16 + ccol;
            int bh = colg >> LP, p = colg & pm;
            __hip_bfloat16* dst = Cc + (size_t)bh*8192 + poff + p;
            #pragma unroll
            for (int j = 0; j < 4; ++j) {
                int r = row0 + m*16 + cr + j;
                dst[r*16] = __float2bfloat16(acc[m][n][j]);
            }
        }
    }
}

// ---------------------------------------------------------------------------
// softmax helper
// ---------------------------------------------------------------------------
template<int L>
__device__ __forceinline__ void softmax2(float2* a) {
    float mx = a[0].x, my = a[0].y;
    #pragma unroll
    for (int j = 1; j < L; ++j) { mx = fmaxf(mx, a[j].x); my = fmaxf(my, a[j].y); }
    float sx = 0.f, sy = 0.f;
    #pragma unroll
    for (int j = 0; j < L; ++j) {
        a[j].x = __expf(a[j].x - mx); sx += a[j].x;
        a[j].y = __expf(a[j].y - my); sy += a[j].y;
    }
    float rx = 1.f / sx, ry = 1.f / sy;
    #pragma unroll
    for (int j = 0; j < L; ++j) { a[j].x *= rx; a[j].y *= ry; }
}

// ---------------------------------------------------------------------------
// k_main v15: block = (b,h). x-row = xT[bh] = 64 KB CONTIGUOUS bf16.
// Each wave DMAs its 16 KB quarter (16 x 1KB) UPFRONT -> 128 KB/CU in flight,
// consumes pass-A with vmcnt ladder (no barriers). 3-sync reduce + softmax.
// Pass B: zero global reads (residual from LDS), strided out writes.
// LDS 64K + 15K = 80896 B -> 2 blocks/CU.
// ---------------------------------------------------------------------------
__global__ __launch_bounds__(256, 2) void k_main(
    const __hip_bfloat16* __restrict__ xT, const __hip_bfloat16* __restrict__ Cc,
    float* __restrict__ out)
{
    int bh = blockIdx.x;
    int b = bh >> 7, h = bh & 127;
    int t = threadIdx.x;
    int lane = t & 63;
    int wv = __builtin_amdgcn_readfirstlane(t >> 6);   // 0..3
    const uint32_t* Cb = (const uint32_t*)(Cc + (size_t)bh*8192);
    const __hip_bfloat16* xrow = xT + (size_t)bh*256*128;
    float2* o2 = (float2*)out + (size_t)b*256*8192 + h*64 + lane;

    __shared__ __hip_bfloat16 xlds[256*128];           // 65536 B
    __shared__ float2 red[2][64][15];                  // 15360 B

    // ---- issue all 16 DMAs for this wave's 64 channels (16 KB) ----
    const __hip_bfloat16* gsrc = xrow + wv*64*128 + lane*8;   // lane*16B
    #pragma unroll
    for (int d = 0; d < 16; ++d) {
        __builtin_amdgcn_global_load_lds(
            (glb_u32_t*)(gsrc + d*4*128),
            (lds_u32_t*)&xlds[(wv*64 + d*4)*128], 16, 0, 0);
    }
    __builtin_amdgcn_sched_barrier(0);

    float2 att[14];
    #pragma unroll
    for (int p = 0; p < 14; ++p) att[p] = make_float2(0.f, 0.f);
    const uint32_t* xl32 = (const uint32_t*)xlds;

    // ---- pass A: vmcnt ladder, 4 channels per step ----
    #define CONSA(D, VM)                                                    \
        asm volatile("s_waitcnt vmcnt(" #VM ")" ::: "memory");              \
        __builtin_amdgcn_sched_barrier(0);                                  \
        {                                                                   \
            const int cb0 = wv*64 + (D)*4;                                  \
            _Pragma("unroll")                                               \
            for (int q = 0; q < 4; ++q) {                                   \
                int c = cb0 + q;                                            \
                const uint32_t* wr = Cb + (size_t)c*8;                      \
                uint32_t xu = xl32[c*64 + lane];                            \
                float2 xv;                                                  \
                xv.x = __uint_as_float(xu << 16);                           \
                xv.y = __uint_as_float(xu & 0xFFFF0000u);                   \
                _Pragma("unroll")                                           \
                for (int p = 0; p < 7; ++p) {                               \
                    uint32_t u = wr[p];                                     \
                    float mlo = __uint_as_float(u << 16);                   \
                    float mhi = __uint_as_float(u & 0xFFFF0000u);           \
                    att[2*p].x   += xv.x * mlo;  att[2*p].y   += xv.y * mlo; \
                    att[2*p+1].x += xv.x * mhi;  att[2*p+1].y += xv.y * mhi; \
                }                                                           \
            }                                                               \
        }

    CONSA(0, 15) CONSA(1, 14) CONSA(2, 13) CONSA(3, 12)
    CONSA(4, 11) CONSA(5, 10) CONSA(6,  9) CONSA(7,  8)
    CONSA(8,  7) CONSA(9,  6) CONSA(10, 5) CONSA(11, 4)
    CONSA(12, 3) CONSA(13, 2) CONSA(14, 1) CONSA(15, 0)
    #undef CONSA

    // ---- cross-wave reduce + softmax ----
    if (wv >= 2) {
        #pragma unroll
        for (int p = 0; p < 14; ++p) red[wv-2][lane][p] = att[p];
    }
    __syncthreads();
    if (wv < 2) {
        #pragma unroll
        for (int p = 0; p < 14; ++p) {
            float2 r = red[wv][lane][p];
            att[p].x += r.x; att[p].y += r.y;
        }
        if (wv == 1) {
            #pragma unroll
            for (int p = 0; p < 14; ++p) red[1][lane][p] = att[p];
        }
    }
    __syncthreads();
    if (wv == 0) {
        #pragma unroll
        for (int p = 0; p < 14; ++p) {
            float2 r = red[1][lane][p];
            att[p].x = (att[p].x + r.x) * 0.0625f;
            att[p].y = (att[p].y + r.y) * 0.0625f;
        }
        softmax2<2>(att + 0);
        softmax2<4>(att + 2);
        softmax2<8>(att + 6);
        #pragma unroll
        for (int p = 0; p < 14; ++p) red[0][lane][p] = att[p];
    }
    __syncthreads();
    #pragma unroll
    for (int p = 0; p < 14; ++p) att[p] = red[0][lane][p];

    // ---- pass B: residual from LDS, strided full-line stores ----
    #pragma unroll 4
    for (int jj = 0; jj < 64; ++jj) {
        int c = wv*64 + jj;
        const uint32_t* wr = Cb + (size_t)(256 + c)*8;
        uint32_t xu = xl32[c*64 + lane];
        float2 acc;
        acc.x = __uint_as_float(xu << 16);
        acc.y = __uint_as_float(xu & 0xFFFF0000u);
        #pragma unroll
        for (int p = 0; p < 7; ++p) {
            uint32_t u = wr[p];
            float vlo = __uint_as_float(u << 16);
            float vhi = __uint_as_float(u & 0xFFFF0000u);
            acc.x += att[2*p].x * vlo + att[2*p+1].x * vhi;
            acc.y += att[2*p].y * vlo + att[2*p+1].y * vhi;
        }
        o2[(size_t)c*8192] = acc;
    }
}

// ---------------------------------------------------------------------------
extern "C" void kernel_launch(void* const* d_in, const int* in_sizes, int n_in,
                              void* d_out, int out_size, void* d_ws, size_t ws_size,
                              hipStream_t stream)
{
    (void)in_sizes; (void)n_in; (void)out_size; (void)ws_size;
    const float* x   = (const float*)d_in[0];
    const float* Wp  = (const float*)d_in[1];
    const float* Wf  = (const float*)d_in[2];
    const float* Wo  = (const float*)d_in[3];
    const float* Wfu = (const float*)d_in[4];
    float* out = (float*)d_out;

    // workspace layout (bytes):
    //   E     fp32 3*MAT          @ 0         =    786432
    //   A     bf16 3*512*256      @ 786432    =    786432
    //   Bt    bf16 28672*256      @ 1572864   =  14680064
    //   Cc    bf16 2048*512*16    @ 16252928  =  33554432  (binsG fp32 aliases;
    //         binsG consumed by k_poolB before k_gemm writes Cc)
    //   xT    bf16 2048*256*128   @ 49807360  = 134217728
    //   total 184 MB (R14's 1.07GB ws poison-fill shows ws_size is ample)
    char* wsb = (char*)d_ws;
    float*          E     = (float*)wsb;
    __hip_bfloat16* A     = (__hip_bfloat16*)(wsb + 786432);
    __hip_bfloat16* Bt    = (__hip_bfloat16*)(wsb + 1572864);
    __hip_bfloat16* Cc    = (__hip_bfloat16*)(wsb + 16252928);
    float*          binsG = (float*)(wsb + 16252928);
    __hip_bfloat16* xT    = (__hip_bfloat16*)(wsb + 49807360);

    k_mats1<<<dim3(6*CC), dim3(256), 0, stream>>>(Wp, Wf, Wo, Wfu, A, E);
    k_mats2<<<dim3(3*CC), dim3(256), 0, stream>>>(Wp, E, A);
    k_trans<<<dim3(2048), dim3(256), 0, stream>>>(x, xT, binsG);
    k_poolB<<<dim3(NBH),  dim3(256), 0, stream>>>(binsG, Bt);
    k_gemm <<<dim3(1792), dim3(128), 0, stream>>>(A, Bt, Cc);
    k_main <<<dim3(NBH),  dim3(256), 0, stream>>>(xT, Cc, out);
}

// Round 16
// 354.883 us; speedup vs baseline: 1.0383x; 1.0383x over previous
//
#include <hip/hip_runtime.h>
#include <hip/hip_bf16.h>
#include <math.h>
#include <stdint.h>

#define CC   256
#define HW   (128*128)       // 16384
#define MAT  (CC*CC)         // 65536
#define NBH  2048
#define N0   4096
#define N1   8192
#define N2   16384

typedef __attribute__((ext_vector_type(8))) short bf16x8;
typedef __attribute__((ext_vector_type(4))) float f32x4;
typedef __attribute__((address_space(3))) uint32_t lds_u32_t;
typedef __attribute__((address_space(1))) const uint32_t glb_u32_t;

// ---------------------------------------------------------------------------
// k_mats1 / k_mats2: tiny weight-product kernels (unchanged).
// ---------------------------------------------------------------------------
__global__ __launch_bounds__(256) void k_mats1(
    const float* __restrict__ Wp, const float* __restrict__ Wf,
    const float* __restrict__ Wo, const float* __restrict__ Wfu,
    __hip_bfloat16* __restrict__ A, float* __restrict__ E)
{
    int idx = blockIdx.x;
    int t = threadIdx.x;
    if (idx < 3*CC) {
        int i = idx >> 8, c = idx & 255;
        const float* wf = Wf + (size_t)i*MAT;
        const float* wp = Wp + (size_t)i*MAT;
        float acc = 0.f;
        for (int o = 0; o < CC; ++o)
            acc += wf[o*CC + c] * wp[o*CC + t];
        A[(size_t)i*512*CC + (size_t)c*CC + t] = __float2bfloat16(acc);
    } else {
        idx -= 3*CC;
        int i = idx >> 8, o = idx & 255;
        const float* wo = Wo + (size_t)i*MAT;
        const float* wfu = Wfu + (size_t)o*(3*CC) + i*CC;
        float acc = 0.f;
        for (int c3 = 0; c3 < CC; ++c3)
            acc += wfu[c3] * wo[c3*CC + t];
        E[(size_t)i*MAT + (size_t)o*CC + t] = acc;
    }
}

__global__ __launch_bounds__(256) void k_mats2(
    const float* __restrict__ Wp, const float* __restrict__ E,
    __hip_bfloat16* __restrict__ A)
{
    int idx = blockIdx.x;
    int i = idx >> 8, o = idx & 255;
    int t = threadIdx.x;
    const float* e = E + (size_t)i*MAT + (size_t)o*CC;
    const float* wp = Wp + (size_t)i*MAT;
    float acc = 0.f;
    for (int c = 0; c < CC; ++c)
        acc += e[c] * wp[c*CC + t];
    A[(size_t)i*512*CC + (size_t)(256+o)*CC + t] = __float2bfloat16(acc);
}

// ---------------------------------------------------------------------------
// k_poolA: one (b,c) per block, 16-deep float4 staging. binsG[b][c][h][8].
// ---------------------------------------------------------------------------
__global__ __launch_bounds__(256, 4) void k_poolA(
    const float* __restrict__ x, float* __restrict__ binsG)
{
    int bc = blockIdx.x;
    int t = threadIdx.x;
    const float4* xp = (const float4*)(x + (size_t)bc*HW) + t;
    __shared__ float bins[128][9];
    float4 v[16];
    #pragma unroll
    for (int i = 0; i < 16; ++i) v[i] = xp[i*256];
    int hb = t >> 5, bin = (t & 31) >> 2;
    #pragma unroll
    for (int i = 0; i < 16; ++i) {
        float s = v[i].x + v[i].y + v[i].z + v[i].w;
        s += __shfl_xor(s, 1);
        s += __shfl_xor(s, 2);
        if ((t & 3) == 0) bins[i*8 + hb][bin] = s;
    }
    __syncthreads();
    int h = t >> 1, b0 = (t & 1) * 4;
    float4 o;
    o.x = bins[h][b0+0]; o.y = bins[h][b0+1];
    o.z = bins[h][b0+2]; o.w = bins[h][b0+3];
    ((float4*)binsG)[(size_t)bc*256 + t] = o;
}

// ---------------------------------------------------------------------------
// k_poolB: binsG -> Bt (bf16), unchanged.
// ---------------------------------------------------------------------------
__global__ __launch_bounds__(256) void k_poolB(
    const float* __restrict__ binsG, __hip_bfloat16* __restrict__ Bt)
{
    int bh = blockIdx.x;
    int b = bh >> 7, h = bh & 127;
    int c = threadIdx.x;
    const float* g = binsG + (((size_t)b*256 + c)*128 + h)*8;
    float4 lo = *(const float4*)(g);
    float4 hi = *(const float4*)(g + 4);
    float b8[8] = {lo.x, lo.y, lo.z, lo.w, hi.x, hi.y, hi.z, hi.w};

    __hip_bfloat16* B0 = Bt;
    __hip_bfloat16* B1 = Bt + (size_t)N0*CC;
    __hip_bfloat16* B2 = Bt + (size_t)(N0+N1)*CC;
    B0[((size_t)bh*2 + 0)*CC + c] = __float2bfloat16((b8[0]+b8[1]+b8[2]+b8[3]) * (1.f/64.f));
    B0[((size_t)bh*2 + 1)*CC + c] = __float2bfloat16((b8[4]+b8[5]+b8[6]+b8[7]) * (1.f/64.f));
    #pragma unroll
    for (int j = 0; j < 4; ++j)
        B1[((size_t)bh*4 + j)*CC + c] = __float2bfloat16((b8[2*j]+b8[2*j+1]) * (1.f/32.f));
    #pragma unroll
    for (int j = 0; j < 8; ++j)
        B2[((size_t)bh*8 + j)*CC + c] = __float2bfloat16(b8[j] * (1.f/16.f));
}

// ---------------------------------------------------------------------------
// k_gemm v2: same MFMA body; epilogue stages 64x64 tile in LDS then writes
// DENSE per-branch arrays: C0[bh][512][2], C1[bh][512][4], C2[bh][512][8]
// (bf16). Kills the 2-byte scatter (dense dwordx4/x2/x1 stores).
// ---------------------------------------------------------------------------
__global__ __launch_bounds__(128) void k_gemm(
    const __hip_bfloat16* __restrict__ A,
    const __hip_bfloat16* __restrict__ Bt,
    __hip_bfloat16* __restrict__ C0,
    __hip_bfloat16* __restrict__ C1,
    __hip_bfloat16* __restrict__ C2)
{
    int blk = blockIdx.x;
    int br, lb;
    if (blk < 256)      { br = 0; lb = blk;       }
    else if (blk < 768) { br = 1; lb = blk - 256; }
    else                { br = 2; lb = blk - 768; }
    size_t aoff  = (size_t)br*512*CC;
    size_t btoff = (br == 0) ? 0 : (br == 1 ? (size_t)N0*CC : (size_t)(N0+N1)*CC);
    const __hip_bfloat16* Ab = A  + aoff;
    const __hip_bfloat16* Bb = Bt + btoff;

    int rb = lb & 3, cb = lb >> 2;
    int wv = threadIdx.x >> 6, lane = threadIdx.x & 63;
    int row0 = rb*128 + wv*64;
    int col0 = cb*64;
    int lr = lane & 15, lk = (lane >> 4) * 8;

    f32x4 acc[4][4] = {};
    for (int kk = 0; kk < CC; kk += 32) {
        bf16x8 af[4], bfr[4];
        #pragma unroll
        for (int m = 0; m < 4; ++m)
            af[m] = *reinterpret_cast<const bf16x8*>(Ab + (size_t)(row0 + m*16 + lr)*CC + kk + lk);
        #pragma unroll
        for (int n = 0; n < 4; ++n)
            bfr[n] = *reinterpret_cast<const bf16x8*>(Bb + (size_t)(col0 + n*16 + lr)*CC + kk + lk);
        #pragma unroll
        for (int m = 0; m < 4; ++m)
            #pragma unroll
            for (int n = 0; n < 4; ++n)
                acc[m][n] = __builtin_amdgcn_mfma_f32_16x16x32_bf16(af[m], bfr[n], acc[m][n], 0, 0, 0);
    }

    // ---- stage tile to LDS (row-major 64x68 ushort, 8B-aligned rows) ----
    __shared__ ushort tile[2][64][68];
    ushort (*tl)[68] = tile[wv];
    int cr = (lane >> 4) * 4, ccol = lane & 15;
    #pragma unroll
    for (int m = 0; m < 4; ++m)
        #pragma unroll
        for (int n = 0; n < 4; ++n)
            #pragma unroll
            for (int j = 0; j < 4; ++j) {
                __hip_bfloat16 hv = __float2bfloat16(acc[m][n][j]);
                tl[m*16 + cr + j][n*16 + ccol] = *(ushort*)&hv;
            }
    // (compiler inserts lgkmcnt waits; tile region is wave-private)

    // ---- dense stores per branch ----
    int r = row0 + lane;                       // this lane's output row
    if (br == 2) {                             // 8 bh, 16B/row each
        #pragma unroll
        for (int ch = 0; ch < 8; ++ch) {
            int bh = cb*8 + ch;
            uint2 a = *(const uint2*)&tl[lane][ch*8];
            uint2 b = *(const uint2*)&tl[lane][ch*8 + 4];
            uint4 v; v.x = a.x; v.y = a.y; v.z = b.x; v.w = b.y;
            *(uint4*)(C2 + ((size_t)bh*512 + r)*8) = v;
        }
    } else if (br == 1) {                      // 16 bh, 8B/row each
        #pragma unroll
        for (int ch = 0; ch < 16; ++ch) {
            int bh = cb*16 + ch;
            uint2 v = *(const uint2*)&tl[lane][ch*4];
            *(uint2*)(C1 + ((size_t)bh*512 + r)*4) = v;
        }
    } else {                                   // 32 bh, 4B/row each
        #pragma unroll
        for (int ch = 0; ch < 32; ++ch) {
            int bh = cb*32 + ch;
            uint32_t v = *(const uint32_t*)&tl[lane][ch*2];
            *(uint32_t*)(C0 + ((size_t)bh*512 + r)*2) = v;
        }
    }
}

// ---------------------------------------------------------------------------
// softmax helper + 14-way FMA from 7 packed-bf16 dwords
// ---------------------------------------------------------------------------
template<int L>
__device__ __forceinline__ void softmax2(float2* a) {
    float mx = a[0].x, my = a[0].y;
    #pragma unroll
    for (int j = 1; j < L; ++j) { mx = fmaxf(mx, a[j].x); my = fmaxf(my, a[j].y); }
    float sx = 0.f, sy = 0.f;
    #pragma unroll
    for (int j = 0; j < L; ++j) {
        a[j].x = __expf(a[j].x - mx); sx += a[j].x;
        a[j].y = __expf(a[j].y - my); sy += a[j].y;
    }
    float rx = 1.f / sx, ry = 1.f / sy;
    #pragma unroll
    for (int j = 0; j < L; ++j) { a[j].x *= rx; a[j].y *= ry; }
}

__device__ __forceinline__ void fma14(
    float2* att, float2 xv, uint32_t w0, uint2 w1, uint4 w2)
{
    uint32_t u[7] = {w0, w1.x, w1.y, w2.x, w2.y, w2.z, w2.w};
    #pragma unroll
    for (int p = 0; p < 7; ++p) {
        float lo = __uint_as_float(u[p] << 16);
        float hi = __uint_as_float(u[p] & 0xFFFF0000u);
        att[2*p].x   += xv.x * lo;  att[2*p].y   += xv.y * lo;
        att[2*p+1].x += xv.x * hi;  att[2*p+1].y += xv.y * hi;
    }
}

// ---------------------------------------------------------------------------
// k_main v9 (R9's proven structure) with per-branch dense weight arrays.
// Free-running waves, global_load_lds ring of 4, prefetch 3, counted vmcnt,
// no per-tile barriers; 3-sync reduce+softmax at the pass boundary.
// ---------------------------------------------------------------------------
__global__ __launch_bounds__(256, 4) void k_main(
    const float* __restrict__ x,
    const __hip_bfloat16* __restrict__ C0,
    const __hip_bfloat16* __restrict__ C1,
    const __hip_bfloat16* __restrict__ C2,
    float* __restrict__ out)
{
    int bh = blockIdx.x;
    int b = bh >> 7, h = bh & 127;
    int t = threadIdx.x;
    int lane = t & 63;
    int wv = __builtin_amdgcn_readfirstlane(t >> 6);
    const uint32_t* C0b = (const uint32_t*)C0 + (size_t)bh*512;  // 1 dw/row
    const uint2*    C1b = (const uint2*)   C1 + (size_t)bh*512;  // 2 dw/row
    const uint4*    C2b = (const uint4*)   C2 + (size_t)bh*512;  // 4 dw/row
    const float* xg = x  + ((size_t)b*CC)*HW + h*128;
    float*       og = out + ((size_t)b*CC)*HW + h*128;

    __shared__ float xbuf[4][32*128];
    __shared__ float att_sx[2][64][15];
    __shared__ float att_sy[2][64][15];

    float2 att[14];
    #pragma unroll
    for (int p = 0; p < 14; ++p) att[p] = make_float2(0.f, 0.f);

    auto STAGE = [&](int tt) {
        int cb = (tt & 7) * 32;
        float* bufp = xbuf[tt & 3];
        #pragma unroll
        for (int q = 0; q < 4; ++q) {
            int c0 = cb + wv*8 + q*2;
            const float* gp = xg + (size_t)(c0 + (lane >> 5))*HW + (lane & 31)*4;
            float* lp = &bufp[(wv*8 + q*2)*128];
            __builtin_amdgcn_global_load_lds((glb_u32_t*)gp, (lds_u32_t*)lp, 16, 0, 0);
        }
    };

    STAGE(0); STAGE(1); STAGE(2);

    #pragma unroll 1
    for (int tt = 0; tt < 16; ++tt) {
        if (tt == 8) {
            if (wv >= 2) {
                #pragma unroll
                for (int p = 0; p < 14; ++p) {
                    att_sx[wv-2][lane][p] = att[p].x;
                    att_sy[wv-2][lane][p] = att[p].y;
                }
            }
            __syncthreads();
            if (wv < 2) {
                #pragma unroll
                for (int p = 0; p < 14; ++p) {
                    att[p].x += att_sx[wv][lane][p];
                    att[p].y += att_sy[wv][lane][p];
                }
                if (wv == 1) {
                    #pragma unroll
                    for (int p = 0; p < 14; ++p) {
                        att_sx[1][lane][p] = att[p].x;
                        att_sy[1][lane][p] = att[p].y;
                    }
                }
            }
            __syncthreads();
            if (wv == 0) {
                #pragma unroll
                for (int p = 0; p < 14; ++p) {
                    att[p].x = (att[p].x + att_sx[1][lane][p]) * 0.0625f;
                    att[p].y = (att[p].y + att_sy[1][lane][p]) * 0.0625f;
                }
                softmax2<2>(att + 0);
                softmax2<4>(att + 2);
                softmax2<8>(att + 6);
                #pragma unroll
                for (int p = 0; p < 14; ++p) {
                    att_sx[0][lane][p] = att[p].x;
                    att_sy[0][lane][p] = att[p].y;
                }
            }
            __syncthreads();
            #pragma unroll
            for (int p = 0; p < 14; ++p) {
                att[p].x = att_sx[0][lane][p];
                att[p].y = att_sy[0][lane][p];
            }
        }

        if (tt < 8)       asm volatile("s_waitcnt vmcnt(8)"  ::: "memory");
        else if (tt < 14) asm volatile("s_waitcnt vmcnt(16)" ::: "memory");
        else if (tt == 14) asm volatile("s_waitcnt vmcnt(12)" ::: "memory");
        else               asm volatile("s_waitcnt vmcnt(8)"  ::: "memory");
        __builtin_amdgcn_sched_barrier(0);

        if (tt + 3 < 16) STAGE(tt + 3);

        {
            int cb = (tt & 7) * 32;
            bool passB = (tt >= 8);
            const float* xb = &xbuf[tt & 3][(wv*8)*128];
            int crow0 = (passB ? 256 : 0) + cb + wv*8;
            #pragma unroll
            for (int q = 0; q < 8; ++q) {
                int crow = crow0 + q;
                uint32_t w0 = C0b[crow];
                uint2    w1 = C1b[crow];
                uint4    w2 = C2b[crow];
                float2 xv = *(const float2*)&xb[q*128 + lane*2];
                if (!passB) {
                    fma14(att, xv, w0, w1, w2);
                } else {
                    float2 acc = xv;
                    uint32_t u[7] = {w0, w1.x, w1.y, w2.x, w2.y, w2.z, w2.w};
                    #pragma unroll
                    for (int p = 0; p < 7; ++p) {
                        float vlo = __uint_as_float(u[p] << 16);
                        float vhi = __uint_as_float(u[p] & 0xFFFF0000u);
                        acc.x += att[2*p].x * vlo + att[2*p+1].x * vhi;
                        acc.y += att[2*p].y * vlo + att[2*p+1].y * vhi;
                    }
                    int o = cb + wv*8 + q;
                    *(float2*)&og[(size_t)o*HW + lane*2] = acc;
                }
            }
        }
    }
}

// ---------------------------------------------------------------------------
extern "C" void kernel_launch(void* const* d_in, const int* in_sizes, int n_in,
                              void* d_out, int out_size, void* d_ws, size_t ws_size,
                              hipStream_t stream)
{
    (void)in_sizes; (void)n_in; (void)out_size; (void)ws_size;
    const float* x   = (const float*)d_in[0];
    const float* Wp  = (const float*)d_in[1];
    const float* Wf  = (const float*)d_in[2];
    const float* Wo  = (const float*)d_in[3];
    const float* Wfu = (const float*)d_in[4];
    float* out = (float*)d_out;

    // workspace layout (bytes):
    //   E     fp32 3*MAT        @ 0        =   786432
    //   A     bf16 3*512*256    @ 786432   =   786432
    //   Bt    bf16 28672*256    @ 1572864  = 14680064
    //   binsG fp32 16*256*128*8 @ 16252928 = 16777216
    //   C0    bf16 2048*512*2   @ 33030144 =  4194304
    //   C1    bf16 2048*512*4   @ 37224448 =  8388608
    //   C2    bf16 2048*512*8   @ 45613056 = 16777216   total ~62.4 MB
    char* wsb = (char*)d_ws;
    float*          E     = (float*)wsb;
    __hip_bfloat16* A     = (__hip_bfloat16*)(wsb + 786432);
    __hip_bfloat16* Bt    = (__hip_bfloat16*)(wsb + 1572864);
    float*          binsG = (float*)(wsb + 16252928);
    __hip_bfloat16* C0    = (__hip_bfloat16*)(wsb + 33030144);
    __hip_bfloat16* C1    = (__hip_bfloat16*)(wsb + 37224448);
    __hip_bfloat16* C2    = (__hip_bfloat16*)(wsb + 45613056);

    k_mats1<<<dim3(6*CC), dim3(256), 0, stream>>>(Wp, Wf, Wo, Wfu, A, E);
    k_mats2<<<dim3(3*CC), dim3(256), 0, stream>>>(Wp, E, A);
    k_poolA<<<dim3(4096), dim3(256), 0, stream>>>(x, binsG);
    k_poolB<<<dim3(NBH),  dim3(256), 0, stream>>>(binsG, Bt);
    k_gemm <<<dim3(1792), dim3(128), 0, stream>>>(A, Bt, C0, C1, C2);
    k_main <<<dim3(NBH),  dim3(256), 0, stream>>>(x, C0, C1, C2, out);
}

// Round 17
// 331.884 us; speedup vs baseline: 1.1102x; 1.0693x over previous
//
#include <hip/hip_runtime.h>
#include <hip/hip_bf16.h>
#include <math.h>
#include <stdint.h>

#define CC   256
#define HW   (128*128)       // 16384
#define MAT  (CC*CC)         // 65536
#define NBH  2048
#define N0   4096
#define N1   8192
#define N2   16384

typedef __attribute__((ext_vector_type(8))) short bf16x8;
typedef __attribute__((ext_vector_type(4))) float f32x4;
typedef __attribute__((address_space(3))) uint32_t lds_u32_t;
typedef __attribute__((address_space(1))) const uint32_t glb_u32_t;

// ---------------------------------------------------------------------------
// k_mats1 / k_mats2: tiny weight-product kernels (unchanged).
// ---------------------------------------------------------------------------
__global__ __launch_bounds__(256) void k_mats1(
    const float* __restrict__ Wp, const float* __restrict__ Wf,
    const float* __restrict__ Wo, const float* __restrict__ Wfu,
    __hip_bfloat16* __restrict__ A, float* __restrict__ E)
{
    int idx = blockIdx.x;
    int t = threadIdx.x;
    if (idx < 3*CC) {
        int i = idx >> 8, c = idx & 255;
        const float* wf = Wf + (size_t)i*MAT;
        const float* wp = Wp + (size_t)i*MAT;
        float acc = 0.f;
        for (int o = 0; o < CC; ++o)
            acc += wf[o*CC + c] * wp[o*CC + t];
        A[(size_t)i*512*CC + (size_t)c*CC + t] = __float2bfloat16(acc);
    } else {
        idx -= 3*CC;
        int i = idx >> 8, o = idx & 255;
        const float* wo = Wo + (size_t)i*MAT;
        const float* wfu = Wfu + (size_t)o*(3*CC) + i*CC;
        float acc = 0.f;
        for (int c3 = 0; c3 < CC; ++c3)
            acc += wfu[c3] * wo[c3*CC + t];
        E[(size_t)i*MAT + (size_t)o*CC + t] = acc;
    }
}

__global__ __launch_bounds__(256) void k_mats2(
    const float* __restrict__ Wp, const float* __restrict__ E,
    __hip_bfloat16* __restrict__ A)
{
    int idx = blockIdx.x;
    int i = idx >> 8, o = idx & 255;
    int t = threadIdx.x;
    const float* e = E + (size_t)i*MAT + (size_t)o*CC;
    const float* wp = Wp + (size_t)i*MAT;
    float acc = 0.f;
    for (int c = 0; c < CC; ++c)
        acc += e[c] * wp[c*CC + t];
    A[(size_t)i*512*CC + (size_t)(256+o)*CC + t] = __float2bfloat16(acc);
}

// ---------------------------------------------------------------------------
// k_poolA: one (b,c) per block, 16-deep float4 staging. binsG[b][c][h][8].
// ---------------------------------------------------------------------------
__global__ __launch_bounds__(256, 4) void k_poolA(
    const float* __restrict__ x, float* __restrict__ binsG)
{
    int bc = blockIdx.x;
    int t = threadIdx.x;
    const float4* xp = (const float4*)(x + (size_t)bc*HW) + t;
    __shared__ float bins[128][9];
    float4 v[16];
    #pragma unroll
    for (int i = 0; i < 16; ++i) v[i] = xp[i*256];
    int hb = t >> 5, bin = (t & 31) >> 2;
    #pragma unroll
    for (int i = 0; i < 16; ++i) {
        float s = v[i].x + v[i].y + v[i].z + v[i].w;
        s += __shfl_xor(s, 1);
        s += __shfl_xor(s, 2);
        if ((t & 3) == 0) bins[i*8 + hb][bin] = s;
    }
    __syncthreads();
    int h = t >> 1, b0 = (t & 1) * 4;
    float4 o;
    o.x = bins[h][b0+0]; o.y = bins[h][b0+1];
    o.z = bins[h][b0+2]; o.w = bins[h][b0+3];
    ((float4*)binsG)[(size_t)bc*256 + t] = o;
}

// ---------------------------------------------------------------------------
// k_poolB: binsG -> Bt (bf16), unchanged.
// ---------------------------------------------------------------------------
__global__ __launch_bounds__(256) void k_poolB(
    const float* __restrict__ binsG, __hip_bfloat16* __restrict__ Bt)
{
    int bh = blockIdx.x;
    int b = bh >> 7, h = bh & 127;
    int c = threadIdx.x;
    const float* g = binsG + (((size_t)b*256 + c)*128 + h)*8;
    float4 lo = *(const float4*)(g);
    float4 hi = *(const float4*)(g + 4);
    float b8[8] = {lo.x, lo.y, lo.z, lo.w, hi.x, hi.y, hi.z, hi.w};

    __hip_bfloat16* B0 = Bt;
    __hip_bfloat16* B1 = Bt + (size_t)N0*CC;
    __hip_bfloat16* B2 = Bt + (size_t)(N0+N1)*CC;
    B0[((size_t)bh*2 + 0)*CC + c] = __float2bfloat16((b8[0]+b8[1]+b8[2]+b8[3]) * (1.f/64.f));
    B0[((size_t)bh*2 + 1)*CC + c] = __float2bfloat16((b8[4]+b8[5]+b8[6]+b8[7]) * (1.f/64.f));
    #pragma unroll
    for (int j = 0; j < 4; ++j)
        B1[((size_t)bh*4 + j)*CC + c] = __float2bfloat16((b8[2*j]+b8[2*j+1]) * (1.f/32.f));
    #pragma unroll
    for (int j = 0; j < 8; ++j)
        B2[((size_t)bh*8 + j)*CC + c] = __float2bfloat16(b8[j] * (1.f/16.f));
}

// ---------------------------------------------------------------------------
// k_gemm v2 (kept): MFMA body + LDS-staged epilogue, dense per-branch stores
// C0[bh][512][2], C1[bh][512][4], C2[bh][512][8] (bf16).
// ---------------------------------------------------------------------------
__global__ __launch_bounds__(128) void k_gemm(
    const __hip_bfloat16* __restrict__ A,
    const __hip_bfloat16* __restrict__ Bt,
    __hip_bfloat16* __restrict__ C0,
    __hip_bfloat16* __restrict__ C1,
    __hip_bfloat16* __restrict__ C2)
{
    int blk = blockIdx.x;
    int br, lb;
    if (blk < 256)      { br = 0; lb = blk;       }
    else if (blk < 768) { br = 1; lb = blk - 256; }
    else                { br = 2; lb = blk - 768; }
    size_t aoff  = (size_t)br*512*CC;
    size_t btoff = (br == 0) ? 0 : (br == 1 ? (size_t)N0*CC : (size_t)(N0+N1)*CC);
    const __hip_bfloat16* Ab = A  + aoff;
    const __hip_bfloat16* Bb = Bt + btoff;

    int rb = lb & 3, cb = lb >> 2;
    int wv = threadIdx.x >> 6, lane = threadIdx.x & 63;
    int row0 = rb*128 + wv*64;
    int col0 = cb*64;
    int lr = lane & 15, lk = (lane >> 4) * 8;

    f32x4 acc[4][4] = {};
    for (int kk = 0; kk < CC; kk += 32) {
        bf16x8 af[4], bfr[4];
        #pragma unroll
        for (int m = 0; m < 4; ++m)
            af[m] = *reinterpret_cast<const bf16x8*>(Ab + (size_t)(row0 + m*16 + lr)*CC + kk + lk);
        #pragma unroll
        for (int n = 0; n < 4; ++n)
            bfr[n] = *reinterpret_cast<const bf16x8*>(Bb + (size_t)(col0 + n*16 + lr)*CC + kk + lk);
        #pragma unroll
        for (int m = 0; m < 4; ++m)
            #pragma unroll
            for (int n = 0; n < 4; ++n)
                acc[m][n] = __builtin_amdgcn_mfma_f32_16x16x32_bf16(af[m], bfr[n], acc[m][n], 0, 0, 0);
    }

    __shared__ ushort tile[2][64][68];
    ushort (*tl)[68] = tile[wv];
    int cr = (lane >> 4) * 4, ccol = lane & 15;
    #pragma unroll
    for (int m = 0; m < 4; ++m)
        #pragma unroll
        for (int n = 0; n < 4; ++n)
            #pragma unroll
            for (int j = 0; j < 4; ++j) {
                __hip_bfloat16 hv = __float2bfloat16(acc[m][n][j]);
                tl[m*16 + cr + j][n*16 + ccol] = *(ushort*)&hv;
            }

    int r = row0 + lane;
    if (br == 2) {
        #pragma unroll
        for (int ch = 0; ch < 8; ++ch) {
            int bh = cb*8 + ch;
            uint2 a = *(const uint2*)&tl[lane][ch*8];
            uint2 b = *(const uint2*)&tl[lane][ch*8 + 4];
            uint4 v; v.x = a.x; v.y = a.y; v.z = b.x; v.w = b.y;
            *(uint4*)(C2 + ((size_t)bh*512 + r)*8) = v;
        }
    } else if (br == 1) {
        #pragma unroll
        for (int ch = 0; ch < 16; ++ch) {
            int bh = cb*16 + ch;
            uint2 v = *(const uint2*)&tl[lane][ch*4];
            *(uint2*)(C1 + ((size_t)bh*512 + r)*4) = v;
        }
    } else {
        #pragma unroll
        for (int ch = 0; ch < 32; ++ch) {
            int bh = cb*32 + ch;
            uint32_t v = *(const uint32_t*)&tl[lane][ch*2];
            *(uint32_t*)(C0 + ((size_t)bh*512 + r)*2) = v;
        }
    }
}

// ---------------------------------------------------------------------------
// softmax helper
// ---------------------------------------------------------------------------
template<int L>
__device__ __forceinline__ void softmax2(float2* a) {
    float mx = a[0].x, my = a[0].y;
    #pragma unroll
    for (int j = 1; j < L; ++j) { mx = fmaxf(mx, a[j].x); my = fmaxf(my, a[j].y); }
    float sx = 0.f, sy = 0.f;
    #pragma unroll
    for (int j = 0; j < L; ++j) {
        a[j].x = __expf(a[j].x - mx); sx += a[j].x;
        a[j].y = __expf(a[j].y - my); sy += a[j].y;
    }
    float rx = 1.f / sx, ry = 1.f / sy;
    #pragma unroll
    for (int j = 0; j < L; ++j) { a[j].x *= rx; a[j].y *= ry; }
}

// ---------------------------------------------------------------------------
// k_main v17: R9's v9 structure EXACTLY, with dense C0/C1/C2 weights loaded
// in R9-style BATCHES: per 4-row half, gather u[4][7] dwords first (wide
// wave-uniform s_loads, latency amortized), then run the FMA loop.
// ---------------------------------------------------------------------------
__global__ __launch_bounds__(256, 4) void k_main(
    const float* __restrict__ x,
    const __hip_bfloat16* __restrict__ C0,
    const __hip_bfloat16* __restrict__ C1,
    const __hip_bfloat16* __restrict__ C2,
    float* __restrict__ out)
{
    int bh = blockIdx.x;
    int b = bh >> 7, h = bh & 127;
    int t = threadIdx.x;
    int lane = t & 63;
    int wv = __builtin_amdgcn_readfirstlane(t >> 6);
    const uint32_t* C0b = (const uint32_t*)C0 + (size_t)bh*512;  // 1 dw/row
    const uint2*    C1b = (const uint2*)   C1 + (size_t)bh*512;  // 2 dw/row
    const uint4*    C2b = (const uint4*)   C2 + (size_t)bh*512;  // 4 dw/row
    const float* xg = x  + ((size_t)b*CC)*HW + h*128;
    float*       og = out + ((size_t)b*CC)*HW + h*128;

    __shared__ float xbuf[4][32*128];
    __shared__ float att_sx[2][64][15];
    __shared__ float att_sy[2][64][15];

    float2 att[14];
    #pragma unroll
    for (int p = 0; p < 14; ++p) att[p] = make_float2(0.f, 0.f);

    auto STAGE = [&](int tt) {
        int cb = (tt & 7) * 32;
        float* bufp = xbuf[tt & 3];
        #pragma unroll
        for (int q = 0; q < 4; ++q) {
            int c0 = cb + wv*8 + q*2;
            const float* gp = xg + (size_t)(c0 + (lane >> 5))*HW + (lane & 31)*4;
            float* lp = &bufp[(wv*8 + q*2)*128];
            __builtin_amdgcn_global_load_lds((glb_u32_t*)gp, (lds_u32_t*)lp, 16, 0, 0);
        }
    };

    STAGE(0); STAGE(1); STAGE(2);

    #pragma unroll 1
    for (int tt = 0; tt < 16; ++tt) {
        if (tt == 8) {
            if (wv >= 2) {
                #pragma unroll
                for (int p = 0; p < 14; ++p) {
                    att_sx[wv-2][lane][p] = att[p].x;
                    att_sy[wv-2][lane][p] = att[p].y;
                }
            }
            __syncthreads();
            if (wv < 2) {
                #pragma unroll
                for (int p = 0; p < 14; ++p) {
                    att[p].x += att_sx[wv][lane][p];
                    att[p].y += att_sy[wv][lane][p];
                }
                if (wv == 1) {
                    #pragma unroll
                    for (int p = 0; p < 14; ++p) {
                        att_sx[1][lane][p] = att[p].x;
                        att_sy[1][lane][p] = att[p].y;
                    }
                }
            }
            __syncthreads();
            if (wv == 0) {
                #pragma unroll
                for (int p = 0; p < 14; ++p) {
                    att[p].x = (att[p].x + att_sx[1][lane][p]) * 0.0625f;
                    att[p].y = (att[p].y + att_sy[1][lane][p]) * 0.0625f;
                }
                softmax2<2>(att + 0);
                softmax2<4>(att + 2);
                softmax2<8>(att + 6);
                #pragma unroll
                for (int p = 0; p < 14; ++p) {
                    att_sx[0][lane][p] = att[p].x;
                    att_sy[0][lane][p] = att[p].y;
                }
            }
            __syncthreads();
            #pragma unroll
            for (int p = 0; p < 14; ++p) {
                att[p].x = att_sx[0][lane][p];
                att[p].y = att_sy[0][lane][p];
            }
        }

        if (tt < 8)       asm volatile("s_waitcnt vmcnt(8)"  ::: "memory");
        else if (tt < 14) asm volatile("s_waitcnt vmcnt(16)" ::: "memory");
        else if (tt == 14) asm volatile("s_waitcnt vmcnt(12)" ::: "memory");
        else               asm volatile("s_waitcnt vmcnt(8)"  ::: "memory");
        __builtin_amdgcn_sched_barrier(0);

        if (tt + 3 < 16) STAGE(tt + 3);

        {
            int cb = (tt & 7) * 32;
            bool passB = (tt >= 8);
            const float* xb = &xbuf[tt & 3][(wv*8)*128];
            int crow0 = (passB ? 256 : 0) + cb + wv*8;
            #pragma unroll
            for (int half = 0; half < 2; ++half) {
                // ---- batched weight gather for 4 rows (R9 pattern) ----
                uint32_t u[4][7];
                #pragma unroll
                for (int q = 0; q < 4; ++q) {
                    int crow = crow0 + half*4 + q;
                    uint32_t w0 = C0b[crow];
                    uint2    w1 = C1b[crow];
                    uint4    w2 = C2b[crow];
                    u[q][0] = w0;
                    u[q][1] = w1.x; u[q][2] = w1.y;
                    u[q][3] = w2.x; u[q][4] = w2.y; u[q][5] = w2.z; u[q][6] = w2.w;
                }
                #pragma unroll
                for (int q = 0; q < 4; ++q) {
                    int qq = half*4 + q;
                    float2 xv = *(const float2*)&xb[qq*128 + lane*2];
                    if (!passB) {
                        #pragma unroll
                        for (int p = 0; p < 7; ++p) {
                            float mlo = __uint_as_float(u[q][p] << 16);
                            float mhi = __uint_as_float(u[q][p] & 0xFFFF0000u);
                            att[2*p].x   += xv.x * mlo;  att[2*p].y   += xv.y * mlo;
                            att[2*p+1].x += xv.x * mhi;  att[2*p+1].y += xv.y * mhi;
                        }
                    } else {
                        float2 acc = xv;
                        #pragma unroll
                        for (int p = 0; p < 7; ++p) {
                            float vlo = __uint_as_float(u[q][p] << 16);
                            float vhi = __uint_as_float(u[q][p] & 0xFFFF0000u);
                            acc.x += att[2*p].x * vlo + att[2*p+1].x * vhi;
                            acc.y += att[2*p].y * vlo + att[2*p+1].y * vhi;
                        }
                        int o = cb + wv*8 + qq;
                        *(float2*)&og[(size_t)o*HW + lane*2] = acc;
                    }
                }
            }
        }
    }
}

// ---------------------------------------------------------------------------
extern "C" void kernel_launch(void* const* d_in, const int* in_sizes, int n_in,
                              void* d_out, int out_size, void* d_ws, size_t ws_size,
                              hipStream_t stream)
{
    (void)in_sizes; (void)n_in; (void)out_size; (void)ws_size;
    const float* x   = (const float*)d_in[0];
    const float* Wp  = (const float*)d_in[1];
    const float* Wf  = (const float*)d_in[2];
    const float* Wo  = (const float*)d_in[3];
    const float* Wfu = (const float*)d_in[4];
    float* out = (float*)d_out;

    // workspace layout (bytes):
    //   E     fp32 3*MAT        @ 0        =   786432
    //   A     bf16 3*512*256    @ 786432   =   786432
    //   Bt    bf16 28672*256    @ 1572864  = 14680064
    //   binsG fp32 16*256*128*8 @ 16252928 = 16777216
    //   C0    bf16 2048*512*2   @ 33030144 =  4194304
    //   C1    bf16 2048*512*4   @ 37224448 =  8388608
    //   C2    bf16 2048*512*8   @ 45613056 = 16777216   total ~62.4 MB
    char* wsb = (char*)d_ws;
    float*          E     = (float*)wsb;
    __hip_bfloat16* A     = (__hip_bfloat16*)(wsb + 786432);
    __hip_bfloat16* Bt    = (__hip_bfloat16*)(wsb + 1572864);
    float*          binsG = (float*)(wsb + 16252928);
    __hip_bfloat16* C0    = (__hip_bfloat16*)(wsb + 33030144);
    __hip_bfloat16* C1    = (__hip_bfloat16*)(wsb + 37224448);
    __hip_bfloat16* C2    = (__hip_bfloat16*)(wsb + 45613056);

    k_mats1<<<dim3(6*CC), dim3(256), 0, stream>>>(Wp, Wf, Wo, Wfu, A, E);
    k_mats2<<<dim3(3*CC), dim3(256), 0, stream>>>(Wp, E, A);
    k_poolA<<<dim3(4096), dim3(256), 0, stream>>>(x, binsG);
    k_poolB<<<dim3(NBH),  dim3(256), 0, stream>>>(binsG, Bt);
    k_gemm <<<dim3(1792), dim3(128), 0, stream>>>(A, Bt, C0, C1, C2);
    k_main <<<dim3(NBH),  dim3(256), 0, stream>>>(x, C0, C1, C2, out);
}